// Round 2
// baseline (397.362 us; speedup 1.0000x reference)
//
#include <hip/hip_runtime.h>
#include <hip/hip_bf16.h>

// x[16,32,32,32,32] f32, w[32,64,3,3,3] f32, b[64] f32
// ConvTranspose3d(s=2,p=1,k=3) -> (+bias)*0.5 -> maxpool2 -> mean -> clamp[0,1] -> out[16,64]
//
// Window algebra (validated R0/R1): window w covers conv outputs {2w,2w+1}/dim,
// inputs {w,w+1}/dim; per-dim (delta,k,parity): (0,1,0) (0,2,1) (1,0,1). No bounds checks.
// MFMA 16x16x32 bf16: M=16 ww-windows, N=16 co, K=32=Cin (layouts verified R1).
//
// R8: pipeline across tiles (theory: R7 showed limiter is stage->barrier->compute
// serialization at ~1.35 waves/SIMD effective occupancy, NOT LDS BW):
//  - block = (b, wd), loops whg 0..3; grid 496 -> ALL blocks co-resident, no tail.
//  - double-buffered LDS xT[2][18432] (72 KB -> 2 blocks/CU); ONE barrier per tile.
//  - async-STAGE split (T14): tile t+1 staged during compute of tile t, in 2-row
//    chunks (16 in-flight VGPRs), inserted at fixed window boundaries, fenced by
//    sched_barrier(0) so loads can't be clustered (reg pressure) or sunk.
//  - 9-chain round-robin MFMA burst + single max3 combine kept from R7.
// Frag rule: tap (kd,kh,kw) uses frag[dd=(kd==0)][dw=(kw==0)] of row win+(kh==0).
//
// ws: [0,4096)B accS[16][64] f32; [4096,...) wB bf16 [cotile4][T27][lane64][j8],
// T in exact consumption order (see TAP tables).

typedef __bf16 bf16x8 __attribute__((ext_vector_type(8)));
typedef float  f32x4  __attribute__((ext_vector_type(4)));
typedef unsigned short ushort_t;
typedef ushort_t ushort8 __attribute__((ext_vector_type(8)));

#define NWIN 29791  // 31^3

__device__ inline ushort_t f2bf(float f) {
    unsigned u = __builtin_bit_cast(unsigned, f);
    u += 0x7FFFu + ((u >> 16) & 1u);   // RNE
    return (ushort_t)(u >> 16);
}

// Consumption-order tap list (kd,kh,kw) for T=0..26
__device__ __constant__ const unsigned char TKD[27] = {2,0,2,0,2,0,2,0, 1,0,1,2,1,0,1,2, 0,1,2,1,0,1,2,1, 0,1,2};
__device__ __constant__ const unsigned char TKH[27] = {0,0,0,0,2,2,2,2, 0,1,0,1,2,1,2,1, 0,1,0,0,2,1,2,2, 1,1,1};
__device__ __constant__ const unsigned char TKW[27] = {0,0,2,2,0,0,2,2, 0,0,2,0,0,2,2,2, 1,0,1,1,1,2,1,1, 1,1,1};

__global__ __launch_bounds__(256) void prep_kernel(const float* __restrict__ w,
                                                   float* __restrict__ ws) {
    int idx = blockIdx.x * 256 + threadIdx.x;
    if (idx < 1024) ws[idx] = 0.f;
    if (idx < 55296) {
        ushort_t* wB = (ushort_t*)((char*)ws + 4096);
        int j = idx & 7;
        int l = (idx >> 3) & 63;
        int q = idx >> 9;           // [0,108) = c*27+T
        int T = q % 27;
        int c = q / 27;
        int ci = ((l >> 4) << 3) + j;
        int co = (c << 4) + (l & 15);
        int k3 = TKD[T] * 9 + TKH[T] * 3 + TKW[T];
        wB[idx] = f2bf(w[(ci * 64 + co) * 27 + k3]);
    }
}

#define MFMA(A, B, C) __builtin_amdgcn_mfma_f32_16x16x32_bf16((A), (B), (C), 0, 0, 0)
#define SB() __builtin_amdgcn_sched_barrier(0)

__device__ __forceinline__ void issue_row(const float* xb2, int voff, int ro, float v[8]) {
#pragma unroll
    for (int i = 0; i < 8; ++i) v[i] = xb2[(size_t)i * 32768u + voff + ro];
}

__device__ __forceinline__ void pack_row(const float v[8], ushort_t* dst) {
    ushort8 pk;
#pragma unroll
    for (int i = 0; i < 4; ++i) {
        __hip_bfloat162 p2 = __float22bfloat162_rn(float2{v[2 * i], v[2 * i + 1]});
        pk[2 * i]     = __builtin_bit_cast(ushort_t, p2.x);
        pk[2 * i + 1] = __builtin_bit_cast(ushort_t, p2.y);
    }
    *(ushort8*)dst = pk;
}

// grid = 16 b * 31 wd, 256 threads; each block loops whg 0..3
__global__ __launch_bounds__(256, 2) void main_kernel(const float* __restrict__ x,
                                                      const float* __restrict__ ws_ro,
                                                      float* __restrict__ accS) {
    __shared__ ushort_t xT[2][18432];  // [buf][dd2][hh9][w32][ci32] bf16, s = kq ^ ((w>>1)&3)

    int bid = blockIdx.x;
    int b   = bid / 31;
    int wd  = bid - b * 31;            // [0,31)
    int tid = threadIdx.x;
    int lane = tid & 63;
    int wave = tid >> 6;
    int uw   = __builtin_amdgcn_readfirstlane(wave);

    // ---- this wave's 27 weight B-frags (consumption order) -> regs, resident for kernel life
    const bf16x8* wBv = (const bf16x8*)((const char*)ws_ro + 4096);
    bf16x8 Bf[27];
#pragma unroll
    for (int t = 0; t < 27; ++t) Bf[t] = wBv[(uw * 27 + t) * 64 + lane];

    // ---- staging lane geometry: wave uw stages ci planes [8uw,8uw+8)
    int ddl = lane >> 5;
    int wl  = lane & 31;
    int sxz = uw ^ ((wl >> 1) & 3);
    int voff = (ddl - 1) * 1024 + wl;
    const float* xbase = x + ((size_t)(b * 32 + uw * 8)) * 32768u + ((size_t)(wd + 1) << 10);
    int dlo = ((ddl * 9) << 10) + (wl << 5) + (sxz << 3);

    // ---- prologue: stage tile whg=0 into buf0 (synchronous)
    {
        ushort_t* dst = &xT[0][dlo];
#pragma unroll
        for (int rr = 0; rr < 9; ++rr) {
            float v[8];
            issue_row(xbase, voff, rr * 32, v);
            pack_row(v, &dst[rr << 10]);
        }
    }
    __syncthreads();

    int m  = lane & 15;
    int kq = lane >> 4;
    float runsum = 0.f;
    const f32x4 Z = (f32x4){0.f, 0.f, 0.f, 0.f};

    float stA[8], stB[8];
    const float* xb2 = xbase;
    ushort_t* dstb = &xT[0][dlo];
    int ro8n = 0;

#pragma unroll 1
    for (int whg = 0; whg < 4; ++whg) {
        const ushort_t* bufc = xT[whg & 1];

        if (whg < 3) {
            int g = whg + 1;
            xb2  = xbase + ((size_t)g << 8);            // + g*8 rows * 32 w
            ro8n = (g == 3) ? 7 * 32 : 8 * 32;          // clamped last row (masked window only)
            dstb = &xT[g & 1][dlo];
            SB();
            issue_row(xb2, voff, 0 * 32, stA);          // chunk rows {0,1}
            issue_row(xb2, voff, 1 * 32, stB);
            SB();
        }

#pragma unroll
        for (int half = 0; half < 2; ++half) {
            int wbase = half << 4;
            int w0 = wbase + m;                    // <= 31
            int w1 = w0 + 1; if (w1 > 31) w1 = 31; // garbage -> window 31, masked
            int col0 = (w0 << 5) + ((kq ^ ((w0 >> 1) & 3)) << 3);
            int col1 = (w1 << 5) + ((kq ^ ((w1 >> 1) & 3)) << 3);
            const ushort_t* p0 = &bufc[col0];
            const ushort_t* p1 = &bufc[col1];

            if (half == 1 && whg < 3) {            // write rows {4,5}, issue {6,7}
                SB();
                pack_row(stA, &dstb[4 << 10]);
                pack_row(stB, &dstb[5 << 10]);
                issue_row(xb2, voff, 6 * 32, stA);
                issue_row(xb2, voff, 7 * 32, stB);
                SB();
            }

            // preload rows 0 (FA) and 1 (FB); indices [dd][dw], dw=1 <-> w-delta 1 (col1)
            bf16x8 FA[2][2], FB[2][2];
#pragma unroll
            for (int dd = 0; dd < 2; ++dd) {
                FA[dd][0] = *(const bf16x8*)&p0[((dd * 9 + 0) << 10)];
                FA[dd][1] = *(const bf16x8*)&p1[((dd * 9 + 0) << 10)];
                FB[dd][0] = *(const bf16x8*)&p0[((dd * 9 + 1) << 10)];
                FB[dd][1] = *(const bf16x8*)&p1[((dd * 9 + 1) << 10)];
            }

#pragma unroll
            for (int win = 0; win < 8; ++win) {
                if (whg < 3) {
                    if (half == 0 && win == 2) {   // write {0,1}, issue {2,3}
                        SB();
                        pack_row(stA, &dstb[0 << 10]);
                        pack_row(stB, &dstb[1 << 10]);
                        issue_row(xb2, voff, 2 * 32, stA);
                        issue_row(xb2, voff, 3 * 32, stB);
                        SB();
                    }
                    if (half == 0 && win == 5) {   // write {2,3}, issue {4,5}
                        SB();
                        pack_row(stA, &dstb[2 << 10]);
                        pack_row(stB, &dstb[3 << 10]);
                        issue_row(xb2, voff, 4 * 32, stA);
                        issue_row(xb2, voff, 5 * 32, stB);
                        SB();
                    }
                    if (half == 1 && win == 3) {   // write {6,7}, issue {8}
                        SB();
                        pack_row(stA, &dstb[6 << 10]);
                        pack_row(stB, &dstb[7 << 10]);
                        issue_row(xb2, voff, ro8n, stA);
                        SB();
                    }
                    if (half == 1 && win == 6) {   // write {8}
                        SB();
                        pack_row(stA, &dstb[8 << 10]);
                        SB();
                    }
                }

                // prefetch row win+2 (consumed next window) before the MFMA burst
                bf16x8 FC[2][2];
                if (win < 7) {
#pragma unroll
                    for (int dd = 0; dd < 2; ++dd) {
                        FC[dd][0] = *(const bf16x8*)&p0[((dd * 9 + win + 2) << 10)];
                        FC[dd][1] = *(const bf16x8*)&p1[((dd * 9 + win + 2) << 10)];
                    }
                }

                // 27 MFMAs, 9 independent chains, round-robin issue.
                // FA = row win (kh in {1,2}); FB = row win+1 (kh==0).
                f32x4 Ca, Cb, Cc, Cd, Ce, Cf, Cg, Ch, Ci;
                // round 1 (chain starts)
                Ca = MFMA(FB[0][1], Bf[0],  Z);   // T0  (2,0,0)
                Cb = MFMA(FB[1][1], Bf[1],  Z);   // T1  (0,0,0)
                Cc = MFMA(FB[0][1], Bf[8],  Z);   // T8  (1,0,0)
                Cd = MFMA(FA[1][1], Bf[9],  Z);   // T9  (0,1,0)
                Ce = MFMA(FB[1][0], Bf[16], Z);   // T16 (0,0,1)
                Cf = MFMA(FA[0][1], Bf[17], Z);   // T17 (1,1,0)
                Cg = MFMA(FB[0][0], Bf[19], Z);   // T19 (1,0,1)
                Ch = MFMA(FA[1][0], Bf[24], Z);   // T24 (0,1,1)
                Ci = MFMA(FA[0][0], Bf[25], Z);   // T25 (1,1,1)
                // round 2
                Ca = MFMA(FB[0][0], Bf[2],  Ca);  // T2  (2,0,2)
                Cb = MFMA(FB[1][0], Bf[3],  Cb);  // T3  (0,0,2)
                Cc = MFMA(FB[0][0], Bf[10], Cc);  // T10 (1,0,2)
                Cd = MFMA(FA[0][1], Bf[11], Cd);  // T11 (2,1,0)
                Ce = MFMA(FB[0][0], Bf[18], Ce);  // T18 (2,0,1)
                Cf = MFMA(FA[0][0], Bf[21], Cf);  // T21 (1,1,2)
                Cg = MFMA(FA[0][0], Bf[23], Cg);  // T23 (1,2,1)
                Ch = MFMA(FA[0][0], Bf[26], Ch);  // T26 (2,1,1)
                // round 3
                Ca = MFMA(FA[0][1], Bf[4],  Ca);  // T4  (2,2,0)
                Cb = MFMA(FA[1][1], Bf[5],  Cb);  // T5  (0,2,0)
                Cc = MFMA(FA[0][1], Bf[12], Cc);  // T12 (1,2,0)
                Cd = MFMA(FA[1][0], Bf[13], Cd);  // T13 (0,1,2)
                Ce = MFMA(FA[1][0], Bf[20], Ce);  // T20 (0,2,1)
                // round 4
                Ca = MFMA(FA[0][0], Bf[6],  Ca);  // T6  (2,2,2)
                Cb = MFMA(FA[1][0], Bf[7],  Cb);  // T7  (0,2,2)
                Cc = MFMA(FA[0][0], Bf[14], Cc);  // T14 (1,2,2)
                Cd = MFMA(FA[0][0], Bf[15], Cd);  // T15 (2,1,2)
                Ce = MFMA(FA[0][0], Bf[22], Ce);  // T22 (2,2,1)

                // single combine: 1 add + max3-shaped tree (8 conv outputs per window)
                f32x4 mx;
#pragma unroll
                for (int i = 0; i < 4; ++i) {
                    float s0 = Ca[i] + Cb[i];                       // class (1,1,1) sum
                    float m1 = fmaxf(fmaxf(s0, Cc[i]), Cd[i]);      // v_max3
                    float m2 = fmaxf(fmaxf(Ce[i], Cf[i]), Cg[i]);   // v_max3
                    float m3 = fmaxf(fmaxf(Ch[i], Ci[i]), m1);      // v_max3
                    mx[i] = fmaxf(m2, m3);
                }

                // masked accumulate: wh = 8*whg + win, rows ww = wbase + kq*4 + rr
                int wh = (whg << 3) + win;
                if (wh < 31) {
#pragma unroll
                    for (int rr = 0; rr < 4; ++rr) {
                        int ww = wbase + (kq << 2) + rr;
                        if (ww < 31) runsum += mx[rr];
                    }
                }

                // rotate rows (pure SSA renaming under full unroll)
                if (win < 7) {
#pragma unroll
                    for (int dd = 0; dd < 2; ++dd)
#pragma unroll
                        for (int dw = 0; dw < 2; ++dw) {
                            FA[dd][dw] = FB[dd][dw];
                            FB[dd][dw] = FC[dd][dw];
                        }
                }
            }
        }

        if (whg < 3) __syncthreads();   // buf[whg+1 & 1] fully written; buf[whg&1] free
    }

    // lanes with same n=(lane&15) hold partials for the same co
    runsum += __shfl_xor(runsum, 16, 64);
    runsum += __shfl_xor(runsum, 32, 64);
    if (lane < 16) atomicAdd(&accS[(b << 6) + (wave << 4) + lane], runsum);
}

__global__ __launch_bounds__(256) void finalize_kernel(const float* __restrict__ accS,
                                                       const float* __restrict__ bias,
                                                       float* __restrict__ out) {
    int i = blockIdx.x * 256 + threadIdx.x;
    if (i < 1024) {
        int co = i & 63;
        float v = (accS[i] * (1.f / (float)NWIN) + bias[co]) * 0.5f;
        v = fminf(fmaxf(v, 0.f), 1.f);
        out[i] = v;
    }
}

extern "C" void kernel_launch(void* const* d_in, const int* in_sizes, int n_in,
                              void* d_out, int out_size, void* d_ws, size_t ws_size,
                              hipStream_t stream) {
    const float* x    = (const float*)d_in[0];
    const float* w    = (const float*)d_in[1];
    const float* bias = (const float*)d_in[2];
    float* out = (float*)d_out;
    float* ws  = (float*)d_ws;

    prep_kernel<<<216, 256, 0, stream>>>(w, ws);
    main_kernel<<<16 * 31, 256, 0, stream>>>(x, ws, ws);
    finalize_kernel<<<4, 256, 0, stream>>>(ws, bias, out);
}

// Round 4
// 251.312 us; speedup vs baseline: 1.5812x; 1.5812x over previous
//
#include <hip/hip_runtime.h>
#include <hip/hip_bf16.h>

// x[16,32,32,32,32] f32, w[32,64,3,3,3] f32, b[64] f32
// ConvTranspose3d(s=2,p=1,k=3) -> (+bias)*0.5 -> maxpool2 -> mean -> clamp[0,1] -> out[16,64]
//
// Window algebra (validated R0/R1): window w covers conv outputs {2w,2w+1}/dim,
// inputs {w,w+1}/dim; per-dim (delta,k,parity): (0,1,0) (0,2,1) (1,0,1).
// MFMA 16x16x32 bf16: M=16 ww-windows, N=16 co, K=32=Cin (layouts verified R1).
//
// R10 == R9 resubmit (R9 bench died to container infra failure, not the kernel;
// bounds/race audit clean). Rolling-h ring buffer:
//  - block = (b, wd) owns ALL 31 h-windows; LDS = 8-row ring (32 KB), slot = h&7.
//  - per 2-window pair: stage 2 rows (16 regs, issue-early/pack-late), compute
//    4 MFMA bursts (~2100 pipe-cyc cover), 1 barrier. Stage cost amortized.
//  - ring safety: pair g reads rows 2g..2g+2, writes slots (2g+4)&7,(2g+5)&7
//    (disjoint mod 8); row 2g+2 written end of pair g-1 + barrier.
//  - no masked wh=31 window (31 iters, -3% MFMA), no last-row clamp, FETCH -11%.
//  - frags read fresh per half (8 ds_read_b128); live set ~215 regs
//    (Bf 108 + F 32 + acc 36 + stage 16 + misc).
// Frag rule: tap (kd,kh,kw) uses frag[dd=(kd==0)][dw=(kw==0)] of row wh+(kh==0).
//
// ws: [0,4096)B accS[16][64] f32; [4096,...) wB bf16 [cotile4][T27][lane64][j8],
// T in exact consumption order (see TAP tables).

typedef __bf16 bf16x8 __attribute__((ext_vector_type(8)));
typedef float  f32x4  __attribute__((ext_vector_type(4)));
typedef unsigned short ushort_t;
typedef ushort_t ushort8 __attribute__((ext_vector_type(8)));

#define NWIN 29791  // 31^3

__device__ inline ushort_t f2bf(float f) {
    unsigned u = __builtin_bit_cast(unsigned, f);
    u += 0x7FFFu + ((u >> 16) & 1u);   // RNE
    return (ushort_t)(u >> 16);
}

// Consumption-order tap list (kd,kh,kw) for T=0..26
__device__ __constant__ const unsigned char TKD[27] = {2,0,2,0,2,0,2,0, 1,0,1,2,1,0,1,2, 0,1,2,1,0,1,2,1, 0,1,2};
__device__ __constant__ const unsigned char TKH[27] = {0,0,0,0,2,2,2,2, 0,1,0,1,2,1,2,1, 0,1,0,0,2,1,2,2, 1,1,1};
__device__ __constant__ const unsigned char TKW[27] = {0,0,2,2,0,0,2,2, 0,0,2,0,0,2,2,2, 1,0,1,1,1,2,1,1, 1,1,1};

__global__ __launch_bounds__(256) void prep_kernel(const float* __restrict__ w,
                                                   float* __restrict__ ws) {
    int idx = blockIdx.x * 256 + threadIdx.x;
    if (idx < 1024) ws[idx] = 0.f;
    if (idx < 55296) {
        ushort_t* wB = (ushort_t*)((char*)ws + 4096);
        int j = idx & 7;
        int l = (idx >> 3) & 63;
        int q = idx >> 9;           // [0,108) = c*27+T
        int T = q % 27;
        int c = q / 27;
        int ci = ((l >> 4) << 3) + j;
        int co = (c << 4) + (l & 15);
        int k3 = TKD[T] * 9 + TKH[T] * 3 + TKW[T];
        wB[idx] = f2bf(w[(ci * 64 + co) * 27 + k3]);
    }
}

#define MFMA(A, B, C) __builtin_amdgcn_mfma_f32_16x16x32_bf16((A), (B), (C), 0, 0, 0)
#define SB() __builtin_amdgcn_sched_barrier(0)

__device__ __forceinline__ void pack_row(const float v[8], ushort_t* dst) {
    ushort8 pk;
#pragma unroll
    for (int i = 0; i < 4; ++i) {
        __hip_bfloat162 p2 = __float22bfloat162_rn(float2{v[2 * i], v[2 * i + 1]});
        pk[2 * i]     = __builtin_bit_cast(ushort_t, p2.x);
        pk[2 * i + 1] = __builtin_bit_cast(ushort_t, p2.y);
    }
    *(ushort8*)dst = pk;
}

// grid = 16 b * 31 wd, 256 threads; block owns all 31 h-windows of its (b,wd)
__global__ __launch_bounds__(256, 2) void main_kernel(const float* __restrict__ x,
                                                      const float* __restrict__ ws_ro,
                                                      float* __restrict__ accS) {
    __shared__ ushort_t xR[16384];  // ring: 8 slots x [dd2][w32][ci32] bf16 = 32 KB
                                    // slot stride 2048 sh, dd stride 1024 sh, w stride 32 sh

    int bid = blockIdx.x;
    int b   = bid / 31;
    int wd  = bid - b * 31;            // [0,31)
    int tid = threadIdx.x;
    int lane = tid & 63;
    int wave = tid >> 6;
    int uw   = __builtin_amdgcn_readfirstlane(wave);

    // ---- this wave's 27 weight B-frags (consumption order) -> regs
    const bf16x8* wBv = (const bf16x8*)((const char*)ws_ro + 4096);
    bf16x8 Bf[27];
#pragma unroll
    for (int t = 0; t < 27; ++t) Bf[t] = wBv[(uw * 27 + t) * 64 + lane];

    // ---- staging geometry: wave uw stages ci octet [8uw,8uw+8); lane = (dd, w)
    int ddl = lane >> 5;
    int wl  = lane & 31;
    int sw  = uw ^ ((wl >> 1) & 3);
    const float* xb = x + (size_t)(b * 32 + uw * 8) * 32768u
                        + (size_t)(wd + ddl) * 1024u + wl;     // plane wd+ddl, h row via +r*32
    ushort_t* dstb = &xR[(ddl << 10) + (wl << 5) + (sw << 3)]; // + slot*2048 per row

    // ---- prologue: stage h rows 0..3 (slots 0..3), synchronous
#pragma unroll
    for (int r = 0; r < 4; ++r) {
        float v[8];
#pragma unroll
        for (int i = 0; i < 8; ++i) v[i] = xb[(size_t)i * 32768u + r * 32];
        pack_row(v, &dstb[r << 11]);
    }
    __syncthreads();

    int m  = lane & 15;
    int kq = lane >> 4;
    float runsum = 0.f;
    const f32x4 Z = (f32x4){0.f, 0.f, 0.f, 0.f};

    // one h-window: rows at ring ushort-offsets rA (row wh), rB (row wh+1)
    auto do_window = [&](int rA, int rB) {
#pragma unroll
        for (int half = 0; half < 2; ++half) {
            int wbase = half << 4;
            int w0 = wbase + m;                    // <= 31
            int w1 = w0 + 1; if (w1 > 31) w1 = 31; // garbage -> window 31, masked
            int col0 = (w0 << 5) + ((kq ^ ((w0 >> 1) & 3)) << 3);
            int col1 = (w1 << 5) + ((kq ^ ((w1 >> 1) & 3)) << 3);
            const ushort_t* pA0 = &xR[rA + col0];
            const ushort_t* pA1 = &xR[rA + col1];
            const ushort_t* pB0 = &xR[rB + col0];
            const ushort_t* pB1 = &xR[rB + col1];

            // FA = row wh (kh in {1,2}); FB = row wh+1 (kh==0); [dd][dw]
            bf16x8 FA[2][2], FB[2][2];
#pragma unroll
            for (int dd = 0; dd < 2; ++dd) {
                FA[dd][0] = *(const bf16x8*)&pA0[dd << 10];
                FA[dd][1] = *(const bf16x8*)&pA1[dd << 10];
                FB[dd][0] = *(const bf16x8*)&pB0[dd << 10];
                FB[dd][1] = *(const bf16x8*)&pB1[dd << 10];
            }

            // 27 MFMAs, 9 independent chains, round-robin issue
            f32x4 Ca, Cb, Cc, Cd, Ce, Cf, Cg, Ch, Ci;
            Ca = MFMA(FB[0][1], Bf[0],  Z);   // T0  (2,0,0)
            Cb = MFMA(FB[1][1], Bf[1],  Z);   // T1  (0,0,0)
            Cc = MFMA(FB[0][1], Bf[8],  Z);   // T8  (1,0,0)
            Cd = MFMA(FA[1][1], Bf[9],  Z);   // T9  (0,1,0)
            Ce = MFMA(FB[1][0], Bf[16], Z);   // T16 (0,0,1)
            Cf = MFMA(FA[0][1], Bf[17], Z);   // T17 (1,1,0)
            Cg = MFMA(FB[0][0], Bf[19], Z);   // T19 (1,0,1)
            Ch = MFMA(FA[1][0], Bf[24], Z);   // T24 (0,1,1)
            Ci = MFMA(FA[0][0], Bf[25], Z);   // T25 (1,1,1)
            Ca = MFMA(FB[0][0], Bf[2],  Ca);  // T2  (2,0,2)
            Cb = MFMA(FB[1][0], Bf[3],  Cb);  // T3  (0,0,2)
            Cc = MFMA(FB[0][0], Bf[10], Cc);  // T10 (1,0,2)
            Cd = MFMA(FA[0][1], Bf[11], Cd);  // T11 (2,1,0)
            Ce = MFMA(FB[0][0], Bf[18], Ce);  // T18 (2,0,1)
            Cf = MFMA(FA[0][0], Bf[21], Cf);  // T21 (1,1,2)
            Cg = MFMA(FA[0][0], Bf[23], Cg);  // T23 (1,2,1)
            Ch = MFMA(FA[0][0], Bf[26], Ch);  // T26 (2,1,1)
            Ca = MFMA(FA[0][1], Bf[4],  Ca);  // T4  (2,2,0)
            Cb = MFMA(FA[1][1], Bf[5],  Cb);  // T5  (0,2,0)
            Cc = MFMA(FA[0][1], Bf[12], Cc);  // T12 (1,2,0)
            Cd = MFMA(FA[1][0], Bf[13], Cd);  // T13 (0,1,2)
            Ce = MFMA(FA[1][0], Bf[20], Ce);  // T20 (0,2,1)
            Ca = MFMA(FA[0][0], Bf[6],  Ca);  // T6  (2,2,2)
            Cb = MFMA(FA[1][0], Bf[7],  Cb);  // T7  (0,2,2)
            Cc = MFMA(FA[0][0], Bf[14], Cc);  // T14 (1,2,2)
            Cd = MFMA(FA[0][0], Bf[15], Cd);  // T15 (2,1,2)
            Ce = MFMA(FA[0][0], Bf[22], Ce);  // T22 (2,2,1)

            // single combine: 1 add + max3-shaped tree (8 conv outputs per window)
            f32x4 mx;
#pragma unroll
            for (int i = 0; i < 4; ++i) {
                float s0 = Ca[i] + Cb[i];                       // class (1,1,1) sum
                float m1 = fmaxf(fmaxf(s0, Cc[i]), Cd[i]);      // v_max3
                float m2 = fmaxf(fmaxf(Ce[i], Cf[i]), Cg[i]);   // v_max3
                float m3 = fmaxf(fmaxf(Ch[i], Ci[i]), m1);      // v_max3
                mx[i] = fmaxf(m2, m3);
            }
#pragma unroll
            for (int rr = 0; rr < 4; ++rr) {
                int ww = wbase + (kq << 2) + rr;
                if (ww < 31) runsum += mx[rr];
            }
        }
    };

    float sv0[8], sv1[8];

#pragma unroll 1
    for (int g = 0; g < 15; ++g) {          // pair g = windows 2g, 2g+1
        if (g < 14) {                       // issue-early: stage rows 2g+4, 2g+5
            int ra = 2 * g + 4;
#pragma unroll
            for (int i = 0; i < 8; ++i) sv0[i] = xb[(size_t)i * 32768u + ra * 32];
#pragma unroll
            for (int i = 0; i < 8; ++i) sv1[i] = xb[(size_t)i * 32768u + ra * 32 + 32];
            SB();
        }

        int wh = 2 * g;
        int r0 = (wh & 7) << 11;
        int r1 = ((wh + 1) & 7) << 11;
        int r2 = ((wh + 2) & 7) << 11;
        do_window(r0, r1);
        do_window(r1, r2);

        if (g < 14) {                       // write-late, then publish
            SB();
            int ra = 2 * g + 4;
            pack_row(sv0, &dstb[(ra & 7) << 11]);
            pack_row(sv1, &dstb[((ra + 1) & 7) << 11]);
            __syncthreads();
        }
    }
    // final window wh=30 (rows 30,31 staged at pair 13)
    do_window(((30) & 7) << 11, ((31) & 7) << 11);

    // lanes with same n=(lane&15) hold partials for the same co
    runsum += __shfl_xor(runsum, 16, 64);
    runsum += __shfl_xor(runsum, 32, 64);
    if (lane < 16) atomicAdd(&accS[(b << 6) + (wave << 4) + lane], runsum);
}

__global__ __launch_bounds__(256) void finalize_kernel(const float* __restrict__ accS,
                                                       const float* __restrict__ bias,
                                                       float* __restrict__ out) {
    int i = blockIdx.x * 256 + threadIdx.x;
    if (i < 1024) {
        int co = i & 63;
        float v = (accS[i] * (1.f / (float)NWIN) + bias[co]) * 0.5f;
        v = fminf(fmaxf(v, 0.f), 1.f);
        out[i] = v;
    }
}

extern "C" void kernel_launch(void* const* d_in, const int* in_sizes, int n_in,
                              void* d_out, int out_size, void* d_ws, size_t ws_size,
                              hipStream_t stream) {
    const float* x    = (const float*)d_in[0];
    const float* w    = (const float*)d_in[1];
    const float* bias = (const float*)d_in[2];
    float* out = (float*)d_out;
    float* ws  = (float*)d_ws;

    prep_kernel<<<216, 256, 0, stream>>>(w, ws);
    main_kernel<<<16 * 31, 256, 0, stream>>>(x, ws, ws);
    finalize_kernel<<<4, 256, 0, stream>>>(ws, bias, out);
}